// Round 1
// baseline (223.327 us; speedup 1.0000x reference)
//
#include <hip/hip_runtime.h>
#include <math.h>

#define NB 32      // BF (bottleneck features)
#define NW 32      // WIDTH (hidden units)
#define ND 3       // data dim
#define PS 264     // per-stage float stride: 32 units * 8 floats + S at [256] (+pad)

// Per-stage packed params, per hidden unit w (8 floats, 32B aligned):
//   [0..2] = 2*log2(e) * W[w][0..2]
//   [3]    = 2*log2(e) * Bb[w]
//   [4..6] = U'[w][0..2]  where U' = U * sigmoid(G)
//   [7]    = s[w] = sum_d W[w][d]*U'[w][d]
// o[256] = S = sum_w s[w]

__global__ void hyper_kernel(const float* __restrict__ w1, const float* __restrict__ b1,
                             const float* __restrict__ w2, const float* __restrict__ b2,
                             const float* __restrict__ wW, const float* __restrict__ bW,
                             const float* __restrict__ wU, const float* __restrict__ bU,
                             const float* __restrict__ wG, const float* __restrict__ bG,
                             const float* __restrict__ wB, const float* __restrict__ bB,
                             float* __restrict__ ws) {
  const int stage = blockIdx.x;
  const float tv[8] = {2.f, 1.5f, 1.5f, 1.f, 1.f, 0.5f, 0.5f, 0.f};
  const float t = tv[stage];
  __shared__ float h1[NB], h2[NB];
  __shared__ float Wl[NW*ND], Ul[NW*ND], Gl[NW*ND], UUl[NW*ND], Bbl[NW], sl[NW];
  const int tid = threadIdx.x;

  if (tid < NB) h1[tid] = tanhf(t * w1[tid] + b1[tid]);
  __syncthreads();
  if (tid < NB) {
    float a = b2[tid];
    for (int j = 0; j < NB; ++j) a = fmaf(w2[tid*NB + j], h1[j], a);
    h2[tid] = tanhf(a);
  }
  __syncthreads();
  // 96 W, 96 U, 96 G, 32 Bb = 320 outputs, each a 32-dot over h2
  for (int idx = tid; idx < 3*NW*ND + NW; idx += blockDim.x) {
    if (idx < 96) {
      float a = bW[idx];
      for (int j = 0; j < NB; ++j) a = fmaf(wW[idx*NB + j], h2[j], a);
      Wl[idx] = a;
    } else if (idx < 192) {
      int i = idx - 96; float a = bU[i];
      for (int j = 0; j < NB; ++j) a = fmaf(wU[i*NB + j], h2[j], a);
      Ul[i] = a;
    } else if (idx < 288) {
      int i = idx - 192; float a = bG[i];
      for (int j = 0; j < NB; ++j) a = fmaf(wG[i*NB + j], h2[j], a);
      Gl[i] = a;
    } else {
      int i = idx - 288; float a = bB[i];
      for (int j = 0; j < NB; ++j) a = fmaf(wB[i*NB + j], h2[j], a);
      Bbl[i] = a;
    }
  }
  __syncthreads();
  for (int idx = tid; idx < NW*ND; idx += blockDim.x)
    UUl[idx] = Ul[idx] / (1.f + expf(-Gl[idx]));   // U * sigmoid(G)
  __syncthreads();

  float* o = ws + stage * PS;
  const float K = 2.885390081777927f;  // 2 * log2(e), folded so tanh uses raw exp2
  if (tid < NW) {
    const int w = tid;
    float s = Wl[3*w+0]*UUl[3*w+0] + Wl[3*w+1]*UUl[3*w+1] + Wl[3*w+2]*UUl[3*w+2];
    sl[w] = s;
    o[w*8+0] = K * Wl[3*w+0];
    o[w*8+1] = K * Wl[3*w+1];
    o[w*8+2] = K * Wl[3*w+2];
    o[w*8+3] = K * Bbl[w];
    o[w*8+4] = UUl[3*w+0];
    o[w*8+5] = UUl[3*w+1];
    o[w*8+6] = UUl[3*w+2];
    o[w*8+7] = s;
  }
  __syncthreads();
  if (tid == 0) {
    float S = 0.f;
    for (int w = 0; w < NW; ++w) S += sl[w];
    o[256] = S;
  }
}

// one func() evaluation: dz (k) and trace, using packed stage params at o
__device__ __forceinline__ void feval(const float* __restrict__ o,
                                      float zx, float zy, float zz,
                                      float& kx, float& ky, float& kz, float& tr) {
  float ax = 0.f, ay = 0.f, az = 0.f, a2 = 0.f;
#pragma unroll
  for (int w = 0; w < NW; ++w) {
    const float* p = o + w*8;
    // pre = 2*log2e*(z.W + Bb)  (scale folded into params)
    float pre = fmaf(zx, p[0], fmaf(zy, p[1], fmaf(zz, p[2], p[3])));
    // tanh(x) = 1 - 2/(exp2(2x*log2e)+1)
    float q = __builtin_amdgcn_exp2f(pre);
    float r = __builtin_amdgcn_rcpf(q + 1.0f);
    float h = fmaf(-2.f, r, 1.f);
    ax = fmaf(h, p[4], ax);
    ay = fmaf(h, p[5], ay);
    az = fmaf(h, p[6], az);
    a2 = fmaf(h*h, p[7], a2);
  }
  const float inv = 1.f / 32.f;
  kx = ax * inv; ky = ay * inv; kz = az * inv;
  tr = (o[256] - a2) * inv;       // sum_w s_w (1-h^2) / 32
}

__global__ __launch_bounds__(256) void ffjord_main(const float* __restrict__ z1,
                                                   const float* __restrict__ ws,
                                                   float* __restrict__ out, int n) {
  int i = blockIdx.x * blockDim.x + threadIdx.x;
  if (i >= n) return;
  float zx = z1[3*i+0], zy = z1[3*i+1], zz = z1[3*i+2];
  float logdet = 0.f;
  // two intervals, each dt = -1, stage params consecutive in ws
  for (int itv = 0; itv < 2; ++itv) {
    const float* b0 = ws + itv * 4 * PS;
    float k1x,k1y,k1z,t1, k2x,k2y,k2z,t2, k3x,k3y,k3z,t3, k4x,k4y,k4z,t4;
    feval(b0,        zx, zy, zz,                                     k1x,k1y,k1z,t1);
    feval(b0 + PS,   fmaf(-0.5f,k1x,zx), fmaf(-0.5f,k1y,zy), fmaf(-0.5f,k1z,zz), k2x,k2y,k2z,t2);
    feval(b0 + 2*PS, fmaf(-0.5f,k2x,zx), fmaf(-0.5f,k2y,zy), fmaf(-0.5f,k2z,zz), k3x,k3y,k3z,t3);
    feval(b0 + 3*PS, zx - k3x, zy - k3y, zz - k3z,                   k4x,k4y,k4z,t4);
    const float c = 1.f / 6.f;
    // z += dt*(k1+2k2+2k3+k4)/6, dt=-1
    zx -= c * (k1x + 2.f*(k2x + k3x) + k4x);
    zy -= c * (k1y + 2.f*(k2y + k3y) + k4y);
    zz -= c * (k1z + 2.f*(k2z + k3z) + k4z);
    // logdet -= dt*(l1+2l2+2l3+l4)/6 with l=-tr, dt=-1  =>  logdet -= sum(tr)/6
    logdet -= c * (t1 + 2.f*(t2 + t3) + t4);
  }
  out[3*i+0] = zx; out[3*i+1] = zy; out[3*i+2] = zz;
  out[3*n + i] = logdet;
}

extern "C" void kernel_launch(void* const* d_in, const int* in_sizes, int n_in,
                              void* d_out, int out_size, void* d_ws, size_t ws_size,
                              hipStream_t stream) {
  const float* z1 = (const float*)d_in[0];
  const float* w1 = (const float*)d_in[1];
  const float* b1 = (const float*)d_in[2];
  const float* w2 = (const float*)d_in[3];
  const float* b2 = (const float*)d_in[4];
  const float* wW = (const float*)d_in[5];
  const float* bW = (const float*)d_in[6];
  const float* wU = (const float*)d_in[7];
  const float* bU = (const float*)d_in[8];
  const float* wG = (const float*)d_in[9];
  const float* bG = (const float*)d_in[10];
  const float* wB = (const float*)d_in[11];
  const float* bB = (const float*)d_in[12];
  float* out = (float*)d_out;
  float* ws  = (float*)d_ws;
  const int n = in_sizes[0] / 3;

  hipLaunchKernelGGL(hyper_kernel, dim3(8), dim3(128), 0, stream,
                     w1, b1, w2, b2, wW, bW, wU, bU, wG, bG, wB, bB, ws);
  hipLaunchKernelGGL(ffjord_main, dim3((n + 255) / 256), dim3(256), 0, stream,
                     z1, ws, out, n);
}

// Round 2
// 99.184 us; speedup vs baseline: 2.2516x; 2.2516x over previous
//
#include <hip/hip_runtime.h>
#include <math.h>

#define NB 32      // BF (bottleneck features)
#define NW 32      // WIDTH (hidden units)
#define ND 3       // data dim
#define PS 264     // per-stage float stride: 32 units * 8 floats + S at [256] (+pad)
#define PPT 4      // points per thread

// Per-stage packed params, per hidden unit w (8 floats, 32B aligned):
//   [0..2] = 2*log2(e) * W[w][0..2]
//   [3]    = 2*log2(e) * Bb[w]
//   [4..6] = U''[w][0..2]  where U'' = U * sigmoid(G) / 32
//   [7]    = s'[w] = (1/32) * sum_d W[w][d]*U'[w][d]
// o[256] = S' = sum_w s'[w]

__global__ void hyper_kernel(const float* __restrict__ w1, const float* __restrict__ b1,
                             const float* __restrict__ w2, const float* __restrict__ b2,
                             const float* __restrict__ wW, const float* __restrict__ bW,
                             const float* __restrict__ wU, const float* __restrict__ bU,
                             const float* __restrict__ wG, const float* __restrict__ bG,
                             const float* __restrict__ wB, const float* __restrict__ bB,
                             float* __restrict__ ws) {
  const int stage = blockIdx.x;
  const float tv[8] = {2.f, 1.5f, 1.5f, 1.f, 1.f, 0.5f, 0.5f, 0.f};
  const float t = tv[stage];
  __shared__ float h1[NB], h2[NB];
  __shared__ float Wl[NW*ND], Ul[NW*ND], Gl[NW*ND], UUl[NW*ND], Bbl[NW], sl[NW];
  const int tid = threadIdx.x;

  if (tid < NB) h1[tid] = tanhf(t * w1[tid] + b1[tid]);
  __syncthreads();
  if (tid < NB) {
    float a = b2[tid];
    for (int j = 0; j < NB; ++j) a = fmaf(w2[tid*NB + j], h1[j], a);
    h2[tid] = tanhf(a);
  }
  __syncthreads();
  for (int idx = tid; idx < 3*NW*ND + NW; idx += blockDim.x) {
    if (idx < 96) {
      float a = bW[idx];
      for (int j = 0; j < NB; ++j) a = fmaf(wW[idx*NB + j], h2[j], a);
      Wl[idx] = a;
    } else if (idx < 192) {
      int i = idx - 96; float a = bU[i];
      for (int j = 0; j < NB; ++j) a = fmaf(wU[i*NB + j], h2[j], a);
      Ul[i] = a;
    } else if (idx < 288) {
      int i = idx - 192; float a = bG[i];
      for (int j = 0; j < NB; ++j) a = fmaf(wG[i*NB + j], h2[j], a);
      Gl[i] = a;
    } else {
      int i = idx - 288; float a = bB[i];
      for (int j = 0; j < NB; ++j) a = fmaf(wB[i*NB + j], h2[j], a);
      Bbl[i] = a;
    }
  }
  __syncthreads();
  for (int idx = tid; idx < NW*ND; idx += blockDim.x)
    UUl[idx] = Ul[idx] / (1.f + expf(-Gl[idx]));   // U * sigmoid(G)
  __syncthreads();

  float* o = ws + stage * PS;
  const float K = 2.885390081777927f;  // 2 * log2(e), folded so tanh uses raw exp2
  const float inv = 1.f / 32.f;
  if (tid < NW) {
    const int w = tid;
    float s = Wl[3*w+0]*UUl[3*w+0] + Wl[3*w+1]*UUl[3*w+1] + Wl[3*w+2]*UUl[3*w+2];
    sl[w] = s;
    o[w*8+0] = K * Wl[3*w+0];
    o[w*8+1] = K * Wl[3*w+1];
    o[w*8+2] = K * Wl[3*w+2];
    o[w*8+3] = K * Bbl[w];
    o[w*8+4] = inv * UUl[3*w+0];
    o[w*8+5] = inv * UUl[3*w+1];
    o[w*8+6] = inv * UUl[3*w+2];
    o[w*8+7] = inv * s;
  }
  __syncthreads();
  if (tid == 0) {
    float S = 0.f;
    for (int w = 0; w < NW; ++w) S += sl[w];
    o[256] = inv * S;
  }
}

// one func() evaluation for PPT points, params from LDS
__device__ __forceinline__ void feval4(const float* __restrict__ p,
                                       const float zx[PPT], const float zy[PPT], const float zz[PPT],
                                       float kx[PPT], float ky[PPT], float kz[PPT], float tr[PPT]) {
  float ax[PPT], ay[PPT], az[PPT], a2[PPT];
#pragma unroll
  for (int j = 0; j < PPT; ++j) { ax[j]=0.f; ay[j]=0.f; az[j]=0.f; a2[j]=0.f; }
  const float Ssc = p[256];
#pragma unroll 8
  for (int w = 0; w < NW; ++w) {
    const float4 A  = *reinterpret_cast<const float4*>(p + w*8);      // K*W, K*Bb
    const float4 Bv = *reinterpret_cast<const float4*>(p + w*8 + 4);  // U'', s'
#pragma unroll
    for (int j = 0; j < PPT; ++j) {
      float pre = fmaf(zx[j], A.x, fmaf(zy[j], A.y, fmaf(zz[j], A.z, A.w)));
      // tanh(x) = 1 - 2/(exp2(2x*log2e)+1), scale folded into params
      float q = __builtin_amdgcn_exp2f(pre);
      float r = __builtin_amdgcn_rcpf(q + 1.0f);
      float h = fmaf(-2.f, r, 1.f);
      ax[j] = fmaf(h, Bv.x, ax[j]);
      ay[j] = fmaf(h, Bv.y, ay[j]);
      az[j] = fmaf(h, Bv.z, az[j]);
      a2[j] = fmaf(h*h, Bv.w, a2[j]);
    }
  }
#pragma unroll
  for (int j = 0; j < PPT; ++j) {
    kx[j] = ax[j]; ky[j] = ay[j]; kz[j] = az[j];
    tr[j] = Ssc - a2[j];
  }
}

__global__ __launch_bounds__(256) void ffjord_main(const float* __restrict__ z1,
                                                   const float* __restrict__ ws,
                                                   float* __restrict__ out, int n) {
  __shared__ __align__(16) float sp[8*PS];
  for (int i = threadIdx.x; i < 8*PS; i += 256) sp[i] = ws[i];
  __syncthreads();

  const int base = blockIdx.x * (256*PPT) + threadIdx.x;
  float zx[PPT], zy[PPT], zz[PPT], ld[PPT];
  bool val[PPT];
#pragma unroll
  for (int j = 0; j < PPT; ++j) {
    int i = base + j*256;
    val[j] = (i < n);
    int ii = val[j] ? i : 0;
    zx[j] = z1[3*ii+0]; zy[j] = z1[3*ii+1]; zz[j] = z1[3*ii+2];
    ld[j] = 0.f;
  }

  for (int itv = 0; itv < 2; ++itv) {
    const float* b0 = sp + itv*4*PS;
    float kx[PPT], ky[PPT], kz[PPT], kt[PPT];
    float accx[PPT], accy[PPT], accz[PPT], acct[PPT];
    float yx[PPT], yy[PPT], yz[PPT];

    // k1
    feval4(b0, zx, zy, zz, kx, ky, kz, kt);
#pragma unroll
    for (int j = 0; j < PPT; ++j) {
      accx[j]=kx[j]; accy[j]=ky[j]; accz[j]=kz[j]; acct[j]=kt[j];
      yx[j]=fmaf(-0.5f,kx[j],zx[j]); yy[j]=fmaf(-0.5f,ky[j],zy[j]); yz[j]=fmaf(-0.5f,kz[j],zz[j]);
    }
    // k2
    feval4(b0 + PS, yx, yy, yz, kx, ky, kz, kt);
#pragma unroll
    for (int j = 0; j < PPT; ++j) {
      accx[j]=fmaf(2.f,kx[j],accx[j]); accy[j]=fmaf(2.f,ky[j],accy[j]);
      accz[j]=fmaf(2.f,kz[j],accz[j]); acct[j]=fmaf(2.f,kt[j],acct[j]);
      yx[j]=fmaf(-0.5f,kx[j],zx[j]); yy[j]=fmaf(-0.5f,ky[j],zy[j]); yz[j]=fmaf(-0.5f,kz[j],zz[j]);
    }
    // k3
    feval4(b0 + 2*PS, yx, yy, yz, kx, ky, kz, kt);
#pragma unroll
    for (int j = 0; j < PPT; ++j) {
      accx[j]=fmaf(2.f,kx[j],accx[j]); accy[j]=fmaf(2.f,ky[j],accy[j]);
      accz[j]=fmaf(2.f,kz[j],accz[j]); acct[j]=fmaf(2.f,kt[j],acct[j]);
      yx[j]=zx[j]-kx[j]; yy[j]=zy[j]-ky[j]; yz[j]=zz[j]-kz[j];
    }
    // k4
    feval4(b0 + 3*PS, yx, yy, yz, kx, ky, kz, kt);
    const float c = 1.f / 6.f;
#pragma unroll
    for (int j = 0; j < PPT; ++j) {
      zx[j] -= c * (accx[j] + kx[j]);
      zy[j] -= c * (accy[j] + ky[j]);
      zz[j] -= c * (accz[j] + kz[j]);
      ld[j] -= c * (acct[j] + kt[j]);
    }
  }

#pragma unroll
  for (int j = 0; j < PPT; ++j) {
    if (val[j]) {
      int i = base + j*256;
      out[3*i+0] = zx[j]; out[3*i+1] = zy[j]; out[3*i+2] = zz[j];
      out[3*n + i] = ld[j];
    }
  }
}

extern "C" void kernel_launch(void* const* d_in, const int* in_sizes, int n_in,
                              void* d_out, int out_size, void* d_ws, size_t ws_size,
                              hipStream_t stream) {
  const float* z1 = (const float*)d_in[0];
  const float* w1 = (const float*)d_in[1];
  const float* b1 = (const float*)d_in[2];
  const float* w2 = (const float*)d_in[3];
  const float* b2 = (const float*)d_in[4];
  const float* wW = (const float*)d_in[5];
  const float* bW = (const float*)d_in[6];
  const float* wU = (const float*)d_in[7];
  const float* bU = (const float*)d_in[8];
  const float* wG = (const float*)d_in[9];
  const float* bG = (const float*)d_in[10];
  const float* wB = (const float*)d_in[11];
  const float* bB = (const float*)d_in[12];
  float* out = (float*)d_out;
  float* ws  = (float*)d_ws;
  const int n = in_sizes[0] / 3;

  hipLaunchKernelGGL(hyper_kernel, dim3(8), dim3(128), 0, stream,
                     w1, b1, w2, b2, wW, bW, wU, bU, wG, bG, wB, bB, ws);
  const int blocks = (n + 256*PPT - 1) / (256*PPT);
  hipLaunchKernelGGL(ffjord_main, dim3(blocks), dim3(256), 0, stream,
                     z1, ws, out, n);
}